// Round 1
// baseline (346.410 us; speedup 1.0000x reference)
//
#include <hip/hip_runtime.h>
#include <math.h>

// Problem dims (fixed by setup_inputs)
#define HW   16384
#define BS   16
#define C    256
#define NQ   100
#define Hh   128
#define Ww   128

// output layout offsets (floats)
#define SIM_OFF   3200                 // after proposal_for_loss [16,100,2]
#define PROPS_OFF (3200 + 26214400)    // after similarity [16,100,16384]

// ---------------- GEMM kernel ----------------
// sim[b][n][k] = sum_c S[n][b][c] * Q[k][b][c]
// tile: BM=128 (hw) x BN=112 (nq padded from 100) x BK=64
#define BM 128
#define BN 112
#define BK 64
#define LDQ 68   // padded leading dim (floats) to avoid bank conflicts
#define LDS_S 68

__global__ __launch_bounds__(256) void gemm_kernel(const float* __restrict__ Q,
                                                   const float* __restrict__ S,
                                                   float* __restrict__ out)
{
    __shared__ float Qs[BM * LDQ];
    __shared__ float Ss[BN * LDS_S];

    const int b   = blockIdx.y;
    const int hw0 = blockIdx.x * BM;
    const int t   = threadIdx.x;     // 0..255
    const int tx  = t & 15;          // hw group (interleaved rows: m = tx + 16*rm)
    const int ty  = t >> 4;          // nq group (n = ty*7 + rn)

    float acc[8][7];
    #pragma unroll
    for (int i = 0; i < 8; ++i)
        #pragma unroll
        for (int j = 0; j < 7; ++j) acc[i][j] = 0.f;

    const int lr = t >> 4;          // staging: row within pass (0..15)
    const int lc = (t & 15) * 4;    // staging: float col (0..60)

    for (int kk0 = 0; kk0 < C; kk0 += BK) {
        // stage Q tile: 128 rows x 64 floats
        #pragma unroll
        for (int p = 0; p < 8; ++p) {
            int r = p * 16 + lr;
            float4 v = *(const float4*)(Q + ((size_t)(hw0 + r) * BS + b) * C + kk0 + lc);
            *(float4*)&Qs[r * LDQ + lc] = v;
        }
        // stage S tile: 112 rows x 64 floats (rows >= NQ zero)
        #pragma unroll
        for (int p = 0; p < 7; ++p) {
            int r = p * 16 + lr;
            float4 v = make_float4(0.f, 0.f, 0.f, 0.f);
            if (r < NQ) v = *(const float4*)(S + ((size_t)r * BS + b) * C + kk0 + lc);
            *(float4*)&Ss[r * LDS_S + lc] = v;
        }
        __syncthreads();

        #pragma unroll 4
        for (int kk = 0; kk < BK; kk += 4) {
            float4 qf[8], sf[7];
            #pragma unroll
            for (int rm = 0; rm < 8; ++rm)
                qf[rm] = *(const float4*)&Qs[(tx + 16 * rm) * LDQ + kk];
            #pragma unroll
            for (int rn = 0; rn < 7; ++rn)
                sf[rn] = *(const float4*)&Ss[(ty * 7 + rn) * LDS_S + kk];
            #pragma unroll
            for (int dk = 0; dk < 4; ++dk)
                #pragma unroll
                for (int rm = 0; rm < 8; ++rm)
                    #pragma unroll
                    for (int rn = 0; rn < 7; ++rn)
                        acc[rm][rn] += ((const float*)&qf[rm])[dk] * ((const float*)&sf[rn])[dk];
        }
        __syncthreads();
    }

    // write similarity
    float* simb = out + SIM_OFF;
    #pragma unroll
    for (int rn = 0; rn < 7; ++rn) {
        int n = ty * 7 + rn;
        if (n < NQ) {
            size_t base = ((size_t)b * NQ + n) * HW + hw0;
            #pragma unroll
            for (int rm = 0; rm < 8; ++rm)
                simb[base + tx + 16 * rm] = acc[rm][rn];
        }
    }
}

// ---------------- row-reduction kernel ----------------
// one block per (b,n) row of similarity: softmax stats + argmax + 3x3 local peak
__global__ __launch_bounds__(256) void reduce_kernel(const float* __restrict__ sim,
                                                     float* __restrict__ out)
{
    __shared__ float rowbuf[HW];     // 64 KB
    __shared__ float s_pm[4];
    __shared__ int   s_pi[4];
    __shared__ float s_red[4][3];
    __shared__ float s_gmax;
    __shared__ int   s_gidx;

    const int row = blockIdx.x;          // b*NQ + n
    const int t   = threadIdx.x;
    const int wid  = t >> 6;
    const int lane = t & 63;
    const float* src = sim + (size_t)row * HW;

    // pass 1: load row -> LDS, track max/argmax (tie: lowest index)
    float vmax = -3.4e38f;
    int   vidx = 0;
    for (int i = t; i < HW; i += 256) {
        float v = src[i];
        rowbuf[i] = v;
        if (v > vmax) { vmax = v; vidx = i; }
    }
    #pragma unroll
    for (int off = 32; off > 0; off >>= 1) {
        float ov = __shfl_down(vmax, off);
        int   oi = __shfl_down(vidx, off);
        if (ov > vmax || (ov == vmax && oi < vidx)) { vmax = ov; vidx = oi; }
    }
    if (lane == 0) { s_pm[wid] = vmax; s_pi[wid] = vidx; }
    __syncthreads();
    if (t == 0) {
        float gm = s_pm[0]; int gi = s_pi[0];
        #pragma unroll
        for (int wv = 1; wv < 4; ++wv) {
            float ov = s_pm[wv]; int oi = s_pi[wv];
            if (ov > gm || (ov == gm && oi < gi)) { gm = ov; gi = oi; }
        }
        s_gmax = gm; s_gidx = gi;
    }
    __syncthreads();
    const float gmax = s_gmax;

    // pass 2: sum exp, coord-weighted sums (from LDS)
    float z = 0.f, wx = 0.f, wy = 0.f;
    for (int i = t; i < HW; i += 256) {
        float e = __expf(rowbuf[i] - gmax);
        z += e;
        float cx = (float)(i & (Ww - 1)) + 0.5f;
        float cy = (float)(i >> 7) + 0.5f;
        wx += e * cx;
        wy += e * cy;
    }
    #pragma unroll
    for (int off = 32; off > 0; off >>= 1) {
        z  += __shfl_down(z, off);
        wx += __shfl_down(wx, off);
        wy += __shfl_down(wy, off);
    }
    if (lane == 0) { s_red[wid][0] = z; s_red[wid][1] = wx; s_red[wid][2] = wy; }
    __syncthreads();

    if (t == 0) {
        float Z = 0.f, WX = 0.f, WY = 0.f;
        #pragma unroll
        for (int wv = 0; wv < 4; ++wv) { Z += s_red[wv][0]; WX += s_red[wv][1]; WY += s_red[wv][2]; }

        // proposal_for_loss
        out[(size_t)row * 2 + 0] = (WX / Z) * (1.0f / (float)Ww);
        out[(size_t)row * 2 + 1] = (WY / Z) * (1.0f / (float)Hh);

        // local 3x3 around argmax; faithful to reshape(bs,nq,w,h): r = k / h in [0,w), c = k % h in [0,h)
        int p  = s_gidx;
        int pr = p / Hh;
        int pc = p % Hh;
        float lsum = 0.f, lwx = 0.f, lwy = 0.f;
        #pragma unroll
        for (int di = -1; di <= 1; ++di) {
            #pragma unroll
            for (int dj = -1; dj <= 1; ++dj) {
                int r = pr + di, c = pc + dj;
                if (r >= 0 && r < Ww && c >= 0 && c < Hh) {
                    int k = r * Hh + c;
                    float e = __expf(rowbuf[k] - gmax);
                    lsum += e;
                    lwx  += e * ((float)(k & (Ww - 1)) + 0.5f);
                    lwy  += e * ((float)(k >> 7) + 0.5f);
                }
            }
        }
        float denom = lsum + 1e-10f * Z;
        out[PROPS_OFF + (size_t)row * 2 + 0] = (lwx / denom) * (1.0f / (float)Ww);
        out[PROPS_OFF + (size_t)row * 2 + 1] = (lwy / denom) * (1.0f / (float)Hh);
    }
}

extern "C" void kernel_launch(void* const* d_in, const int* in_sizes, int n_in,
                              void* d_out, int out_size, void* d_ws, size_t ws_size,
                              hipStream_t stream) {
    const float* Q = (const float*)d_in[0];   // [hw, bs, c]
    const float* S = (const float*)d_in[1];   // [nq, bs, c]
    float* out = (float*)d_out;

    gemm_kernel<<<dim3(HW / BM, BS), 256, 0, stream>>>(Q, S, out);
    reduce_kernel<<<dim3(BS * NQ), 256, 0, stream>>>(out + SIM_OFF, out);
}

// Round 2
// 138.099 us; speedup vs baseline: 2.5084x; 2.5084x over previous
//
#include <hip/hip_runtime.h>
#include <math.h>

// Problem dims (fixed by setup_inputs)
#define HW   16384
#define BS   16
#define C    256
#define NQ   100
#define Hh   128
#define Ww   128

// output layout offsets (floats)
#define SIM_OFF   3200                 // after proposal_for_loss [16,100,2]
#define PROPS_OFF (3200 + 26214400)    // after similarity [16,100,16384]

typedef _Float16 half8 __attribute__((ext_vector_type(8)));
typedef float f32x4 __attribute__((ext_vector_type(4)));

// ---------------- split-fp16 MFMA GEMM ----------------
// sim[b][n][k] = sum_c S[n][b][c] * Q[k][b][c]
// A = S (M=nq, padded 112 = 7 frags), B = Q (N=hw, 256/block = 4 frags/wave)
#define BM 256     // hw per block
#define BK 32      // k per step
#define LDH 40     // padded LDS row stride (halves): 80 B

__device__ __forceinline__ void cvt_store(_Float16* dhi, _Float16* dlo, float4 v) {
    _Float16 h0 = (_Float16)v.x, h1 = (_Float16)v.y, h2 = (_Float16)v.z, h3 = (_Float16)v.w;
    _Float16 l0 = (_Float16)(v.x - (float)h0), l1 = (_Float16)(v.y - (float)h1);
    _Float16 l2 = (_Float16)(v.z - (float)h2), l3 = (_Float16)(v.w - (float)h3);
    _Float16 hb[4] = {h0, h1, h2, h3};
    _Float16 lb[4] = {l0, l1, l2, l3};
    *(uint2*)dhi = *(uint2*)hb;
    *(uint2*)dlo = *(uint2*)lb;
}

__global__ __launch_bounds__(256, 2) void gemm_kernel(const float* __restrict__ Q,
                                                      const float* __restrict__ S,
                                                      float* __restrict__ out)
{
    __shared__ __align__(16) _Float16 Qhi[BM][LDH];
    __shared__ __align__(16) _Float16 Qlo[BM][LDH];
    __shared__ __align__(16) _Float16 Shi[112][LDH];
    __shared__ __align__(16) _Float16 Slo[112][LDH];

    const int b    = blockIdx.y;
    const int hw0  = blockIdx.x * BM;
    const int t    = threadIdx.x;
    const int wid  = t >> 6;
    const int lane = t & 63;
    const int lr   = lane & 15;    // row (A) / col (B) within fragment
    const int lg   = lane >> 4;    // k-group

    f32x4 acc[7][4];
    #pragma unroll
    for (int n = 0; n < 7; ++n)
        #pragma unroll
        for (int m = 0; m < 4; ++m)
            acc[n][m] = (f32x4)(0.f);

    // staging decomposition: idx -> row = idx>>3, c4 = idx&7  (32 floats = 8 float4 per row)
    const int srow_ = t >> 3;
    const int sc4_  = t & 7;

    for (int k0 = 0; k0 < C; k0 += BK) {
        // ---- stage Q tile: 256 rows x 32 floats, coalesced (8 lanes per row) ----
        #pragma unroll
        for (int p = 0; p < 8; ++p) {
            int row = p * 32 + srow_;
            float4 v = *(const float4*)(Q + ((size_t)(hw0 + row) * BS + b) * C + k0 + sc4_ * 4);
            cvt_store(&Qhi[row][sc4_ * 4], &Qlo[row][sc4_ * 4], v);
        }
        // ---- stage S tile: 112 rows x 32 floats (rows >= NQ zero) ----
        #pragma unroll
        for (int p = 0; p < 4; ++p) {
            int idx = p * 256 + t;
            if (idx < 112 * 8) {
                int row = idx >> 3, c4 = idx & 7;
                float4 v = make_float4(0.f, 0.f, 0.f, 0.f);
                if (row < NQ) v = *(const float4*)(S + ((size_t)row * BS + b) * C + k0 + c4 * 4);
                cvt_store(&Shi[row][c4 * 4], &Slo[row][c4 * 4], v);
            }
        }
        __syncthreads();

        // ---- B fragments (Q): col = wid*64 + 16m + lr, k = 8*lg + j ----
        half8 bhi[4], blo[4];
        #pragma unroll
        for (int m = 0; m < 4; ++m) {
            bhi[m] = *(const half8*)&Qhi[wid * 64 + 16 * m + lr][8 * lg];
            blo[m] = *(const half8*)&Qlo[wid * 64 + 16 * m + lr][8 * lg];
        }
        // ---- A fragments (S) + 3-pass MFMA ----
        #pragma unroll
        for (int n = 0; n < 7; ++n) {
            half8 ahi = *(const half8*)&Shi[16 * n + lr][8 * lg];
            half8 alo = *(const half8*)&Slo[16 * n + lr][8 * lg];
            #pragma unroll
            for (int m = 0; m < 4; ++m) {
                acc[n][m] = __builtin_amdgcn_mfma_f32_16x16x32_f16(ahi, bhi[m], acc[n][m], 0, 0, 0);
                acc[n][m] = __builtin_amdgcn_mfma_f32_16x16x32_f16(ahi, blo[m], acc[n][m], 0, 0, 0);
                acc[n][m] = __builtin_amdgcn_mfma_f32_16x16x32_f16(alo, bhi[m], acc[n][m], 0, 0, 0);
            }
        }
        __syncthreads();
    }

    // ---- epilogue: C/D layout col=lane&15, row=4*(lane>>4)+j ----
    float* simb = out + SIM_OFF;
    #pragma unroll
    for (int n = 0; n < 7; ++n) {
        #pragma unroll
        for (int j = 0; j < 4; ++j) {
            int row = 16 * n + 4 * lg + j;
            if (row < NQ) {
                size_t base = ((size_t)(b * NQ + row)) * HW + hw0 + wid * 64 + lr;
                #pragma unroll
                for (int m = 0; m < 4; ++m)
                    simb[base + 16 * m] = acc[n][m][j];
            }
        }
    }
}

// ---------------- row-reduction kernel ----------------
__global__ __launch_bounds__(256) void reduce_kernel(const float* __restrict__ sim,
                                                     float* __restrict__ out)
{
    __shared__ float rowbuf[HW];     // 64 KB
    __shared__ float s_pm[4];
    __shared__ int   s_pi[4];
    __shared__ float s_red[4][3];
    __shared__ float s_gmax;
    __shared__ int   s_gidx;

    const int row = blockIdx.x;          // b*NQ + n
    const int t   = threadIdx.x;
    const int wid  = t >> 6;
    const int lane = t & 63;
    const float4* src4 = (const float4*)(sim + (size_t)row * HW);

    // pass 1: load row (float4) -> LDS, track max/argmax (tie: lowest index)
    float vmax = -3.4e38f;
    int   vidx = 0;
    #pragma unroll
    for (int p = 0; p < 16; ++p) {
        int i4 = p * 256 + t;
        float4 v = src4[i4];
        *(float4*)&rowbuf[i4 * 4] = v;
        int base = i4 * 4;
        if (v.x > vmax) { vmax = v.x; vidx = base; }
        if (v.y > vmax) { vmax = v.y; vidx = base + 1; }
        if (v.z > vmax) { vmax = v.z; vidx = base + 2; }
        if (v.w > vmax) { vmax = v.w; vidx = base + 3; }
    }
    #pragma unroll
    for (int off = 32; off > 0; off >>= 1) {
        float ov = __shfl_down(vmax, off);
        int   oi = __shfl_down(vidx, off);
        if (ov > vmax || (ov == vmax && oi < vidx)) { vmax = ov; vidx = oi; }
    }
    if (lane == 0) { s_pm[wid] = vmax; s_pi[wid] = vidx; }
    __syncthreads();
    if (t == 0) {
        float gm = s_pm[0]; int gi = s_pi[0];
        #pragma unroll
        for (int wv = 1; wv < 4; ++wv) {
            float ov = s_pm[wv]; int oi = s_pi[wv];
            if (ov > gm || (ov == gm && oi < gi)) { gm = ov; gi = oi; }
        }
        s_gmax = gm; s_gidx = gi;
    }
    __syncthreads();
    const float gmax = s_gmax;

    // pass 2: sum exp, coord-weighted sums (from LDS, float4)
    float z = 0.f, wx = 0.f, wy = 0.f;
    #pragma unroll
    for (int p = 0; p < 16; ++p) {
        int i4 = p * 256 + t;
        float4 v = *(const float4*)&rowbuf[i4 * 4];
        int i = i4 * 4;
        float e0 = __expf(v.x - gmax), e1 = __expf(v.y - gmax);
        float e2 = __expf(v.z - gmax), e3 = __expf(v.w - gmax);
        z += (e0 + e1) + (e2 + e3);
        float cy = (float)(i >> 7) + 0.5f;           // same row of 128 for all 4
        float cx0 = (float)(i & (Ww - 1)) + 0.5f;
        wx += e0 * cx0 + e1 * (cx0 + 1.f) + e2 * (cx0 + 2.f) + e3 * (cx0 + 3.f);
        wy += (e0 + e1 + e2 + e3) * cy;
    }
    #pragma unroll
    for (int off = 32; off > 0; off >>= 1) {
        z  += __shfl_down(z, off);
        wx += __shfl_down(wx, off);
        wy += __shfl_down(wy, off);
    }
    if (lane == 0) { s_red[wid][0] = z; s_red[wid][1] = wx; s_red[wid][2] = wy; }
    __syncthreads();

    if (t == 0) {
        float Z = 0.f, WX = 0.f, WY = 0.f;
        #pragma unroll
        for (int wv = 0; wv < 4; ++wv) { Z += s_red[wv][0]; WX += s_red[wv][1]; WY += s_red[wv][2]; }

        out[(size_t)row * 2 + 0] = (WX / Z) * (1.0f / (float)Ww);
        out[(size_t)row * 2 + 1] = (WY / Z) * (1.0f / (float)Hh);

        // local 3x3 around argmax (reshape(bs,nq,w,h) semantics: r = k / 128, c = k % 128)
        int p  = s_gidx;
        int pr = p / Hh;
        int pc = p % Hh;
        float lsum = 0.f, lwx = 0.f, lwy = 0.f;
        #pragma unroll
        for (int di = -1; di <= 1; ++di) {
            #pragma unroll
            for (int dj = -1; dj <= 1; ++dj) {
                int r = pr + di, c = pc + dj;
                if (r >= 0 && r < Ww && c >= 0 && c < Hh) {
                    int k = r * Hh + c;
                    float e = __expf(rowbuf[k] - gmax);
                    lsum += e;
                    lwx  += e * ((float)(k & (Ww - 1)) + 0.5f);
                    lwy  += e * ((float)(k >> 7) + 0.5f);
                }
            }
        }
        float denom = lsum + 1e-10f * Z;
        out[PROPS_OFF + (size_t)row * 2 + 0] = (lwx / denom) * (1.0f / (float)Ww);
        out[PROPS_OFF + (size_t)row * 2 + 1] = (lwy / denom) * (1.0f / (float)Hh);
    }
}

extern "C" void kernel_launch(void* const* d_in, const int* in_sizes, int n_in,
                              void* d_out, int out_size, void* d_ws, size_t ws_size,
                              hipStream_t stream) {
    const float* Q = (const float*)d_in[0];   // [hw, bs, c]
    const float* S = (const float*)d_in[1];   // [nq, bs, c]
    float* out = (float*)d_out;

    gemm_kernel<<<dim3(HW / BM, BS), 256, 0, stream>>>(Q, S, out);
    reduce_kernel<<<dim3(BS * NQ), 256, 0, stream>>>(out + SIM_OFF, out);
}

// Round 3
// 117.467 us; speedup vs baseline: 2.9490x; 1.1756x over previous
//
#include <hip/hip_runtime.h>
#include <math.h>

// Problem dims (fixed by setup_inputs)
#define HW   16384
#define BS   16
#define C    256
#define NQ   100
#define NQP  112          // padded nq (7 x 16)
#define Hh   128
#define Ww   128

// output layout offsets (floats)
#define SIM_OFF   3200                 // after proposal_for_loss [16,100,2]
#define PROPS_OFF (3200 + 26214400)    // after similarity [16,100,16384]

#define BM 256     // hw per block
#define BK 32      // k per step (== MFMA K)

typedef _Float16 half8 __attribute__((ext_vector_type(8)));
typedef float f32x4 __attribute__((ext_vector_type(4)));

__device__ __forceinline__ void gll16(const void* gp, void* lp) {
    __builtin_amdgcn_global_load_lds((const __attribute__((address_space(1))) void*)gp,
                                     (__attribute__((address_space(3))) void*)lp, 16, 0, 0);
}

__device__ __forceinline__ void split8(const float4 a, const float4 b, half8& hi, half8& lo) {
    float f[8] = {a.x, a.y, a.z, a.w, b.x, b.y, b.z, b.w};
    _Float16 h[8], l[8];
    #pragma unroll
    for (int i = 0; i < 8; ++i) {
        h[i] = (_Float16)f[i];
        l[i] = (_Float16)(f[i] - (float)h[i]);
    }
    hi = *(half8*)h;
    lo = *(half8*)l;
}

// ---------------- S pre-split kernel ----------------
// S [nq, bs, c] fp32 -> Shi/Slo [bs][112][256] fp16 (rows >= NQ zero)
__global__ __launch_bounds__(256) void split_S_kernel(const float* __restrict__ S,
                                                      _Float16* __restrict__ shi,
                                                      _Float16* __restrict__ slo)
{
    int idx4 = blockIdx.x * 256 + threadIdx.x;     // handles 4 elems
    int idx = idx4 * 4;
    if (idx >= BS * NQP * C) return;
    int b = idx / (NQP * C);
    int rem = idx - b * (NQP * C);
    int n = rem / C;
    int k = rem - n * C;
    float4 v = make_float4(0.f, 0.f, 0.f, 0.f);
    if (n < NQ) v = *(const float4*)(S + ((size_t)n * BS + b) * C + k);
    _Float16 h[4], l[4];
    float f[4] = {v.x, v.y, v.z, v.w};
    #pragma unroll
    for (int i = 0; i < 4; ++i) {
        h[i] = (_Float16)f[i];
        l[i] = (_Float16)(f[i] - (float)h[i]);
    }
    *(uint2*)(shi + idx) = *(uint2*)h;
    *(uint2*)(slo + idx) = *(uint2*)l;
}

// ---------------- split-fp16 MFMA GEMM ----------------
// sim[b][n][k] = sum_c S[n][b][c] * Q[k][b][c]
// A = S (M = 112 = 7 frags, all per wave), B = Q (64 hw-cols per wave = 4 frags)
template<bool USE_WS>
__global__ __launch_bounds__(256, 2) void gemm_kernel(const float* __restrict__ Q,
                                                      const float* __restrict__ S,
                                                      const _Float16* __restrict__ ShiG,
                                                      const _Float16* __restrict__ SloG,
                                                      float* __restrict__ out)
{
    // Qf: 256 rows x 32 f32 (128 B row). chunk c (16B) stored at slot c ^ (row&7).
    __shared__ __align__(16) float    Qf[BM * BK];         // 32 KB
    // SHI/SLO: 112 rows x 32 f16 (64 B row). chunk c (16B) at slot c ^ ((row>>1)&3).
    __shared__ __align__(16) _Float16 SHI[NQP * BK];       // 7 KB
    __shared__ __align__(16) _Float16 SLO[NQP * BK];       // 7 KB

    const int b    = blockIdx.y;
    const int hw0  = blockIdx.x * BM;
    const int t    = threadIdx.x;
    const int wid  = t >> 6;
    const int lane = t & 63;
    const int lr   = lane & 15;    // A-row / B-col within fragment
    const int lg   = lane >> 4;    // k-group (0..3)

    f32x4 acc[7][4];
    #pragma unroll
    for (int n = 0; n < 7; ++n)
        #pragma unroll
        for (int m = 0; m < 4; ++m)
            acc[n][m] = (f32x4)(0.f);

    // staging lane decomposition
    const int q_r8  = lane >> 3;                   // row within 8-row group
    const int q_gc  = (lane & 7) ^ q_r8;           // pre-swizzled global chunk (f32 x4)
    const int s_r   = lane >> 2;                   // row within 16-row group
    const int s_gc  = (lane & 3) ^ ((lane >> 3) & 3); // pre-swizzled global chunk (f16 x8)

    for (int k0 = 0; k0 < C; k0 += BK) {
        // ---- stage Q tile via global_load_lds (8 insts/thread, 8 rows each) ----
        #pragma unroll
        for (int p = 0; p < 8; ++p) {
            int rt = wid * 64 + p * 8;             // tile row base (multiple of 8)
            const float* g = Q + ((size_t)(hw0 + rt + q_r8) * BS + b) * C + k0 + q_gc * 4;
            gll16(g, &Qf[rt * BK]);
        }
        // ---- stage S hi/lo tiles (pre-split) ----
        if (USE_WS) {
            for (int i = wid; i < 14; i += 4) {
                _Float16* arr = (i < 7) ? SHI : SLO;
                const _Float16* src = (i < 7) ? ShiG : SloG;
                int r0 = (i % 7) * 16;
                const _Float16* g = src + ((size_t)b * NQP + r0 + s_r) * C + k0 + s_gc * 8;
                gll16(g, &arr[r0 * BK]);
            }
        }
        __syncthreads();

        // ---- B fragments (Q): read f32 swizzled chunks, split hi/lo ----
        half8 bhi[4], blo[4];
        #pragma unroll
        for (int m = 0; m < 4; ++m) {
            int row = wid * 64 + 16 * m + lr;
            int r7 = row & 7;
            float4 qa = *(const float4*)&Qf[row * BK + (((2 * lg + 0) ^ r7) << 2)];
            float4 qb = *(const float4*)&Qf[row * BK + (((2 * lg + 1) ^ r7) << 2)];
            split8(qa, qb, bhi[m], blo[m]);
        }

        // ---- A fragments + 3-pass MFMA ----
        #pragma unroll
        for (int n = 0; n < 7; ++n) {
            int row = 16 * n + lr;
            half8 ahi, alo;
            if (USE_WS) {
                int slot = lg ^ ((row >> 1) & 3);
                ahi = *(const half8*)&SHI[row * BK + slot * 8];
                alo = *(const half8*)&SLO[row * BK + slot * 8];
            } else {
                if (row < NQ) {
                    const float* g = S + ((size_t)row * BS + b) * C + k0 + 8 * lg;
                    float4 sa = *(const float4*)g;
                    float4 sb = *(const float4*)(g + 4);
                    split8(sa, sb, ahi, alo);
                } else {
                    ahi = (half8)(_Float16)0.f;
                    alo = (half8)(_Float16)0.f;
                }
            }
            #pragma unroll
            for (int m = 0; m < 4; ++m) {
                acc[n][m] = __builtin_amdgcn_mfma_f32_16x16x32_f16(ahi, bhi[m], acc[n][m], 0, 0, 0);
                acc[n][m] = __builtin_amdgcn_mfma_f32_16x16x32_f16(ahi, blo[m], acc[n][m], 0, 0, 0);
                acc[n][m] = __builtin_amdgcn_mfma_f32_16x16x32_f16(alo, bhi[m], acc[n][m], 0, 0, 0);
            }
        }
        __syncthreads();
    }

    // ---- epilogue: C/D layout col = lane&15, row = 4*(lane>>4)+j ----
    float* simb = out + SIM_OFF;
    #pragma unroll
    for (int n = 0; n < 7; ++n) {
        #pragma unroll
        for (int j = 0; j < 4; ++j) {
            int row = 16 * n + 4 * lg + j;
            if (row < NQ) {
                size_t base = ((size_t)(b * NQ + row)) * HW + hw0 + wid * 64 + lr;
                #pragma unroll
                for (int m = 0; m < 4; ++m)
                    simb[base + 16 * m] = acc[n][m][j];
            }
        }
    }
}

// ---------------- row-reduction kernel ----------------
__global__ __launch_bounds__(256) void reduce_kernel(const float* __restrict__ sim,
                                                     float* __restrict__ out)
{
    __shared__ float rowbuf[HW];     // 64 KB
    __shared__ float s_pm[4];
    __shared__ int   s_pi[4];
    __shared__ float s_red[4][3];
    __shared__ float s_gmax;
    __shared__ int   s_gidx;

    const int row = blockIdx.x;          // b*NQ + n
    const int t   = threadIdx.x;
    const int wid  = t >> 6;
    const int lane = t & 63;
    const float4* src4 = (const float4*)(sim + (size_t)row * HW);

    float vmax = -3.4e38f;
    int   vidx = 0;
    #pragma unroll
    for (int p = 0; p < 16; ++p) {
        int i4 = p * 256 + t;
        float4 v = src4[i4];
        *(float4*)&rowbuf[i4 * 4] = v;
        int base = i4 * 4;
        if (v.x > vmax) { vmax = v.x; vidx = base; }
        if (v.y > vmax) { vmax = v.y; vidx = base + 1; }
        if (v.z > vmax) { vmax = v.z; vidx = base + 2; }
        if (v.w > vmax) { vmax = v.w; vidx = base + 3; }
    }
    #pragma unroll
    for (int off = 32; off > 0; off >>= 1) {
        float ov = __shfl_down(vmax, off);
        int   oi = __shfl_down(vidx, off);
        if (ov > vmax || (ov == vmax && oi < vidx)) { vmax = ov; vidx = oi; }
    }
    if (lane == 0) { s_pm[wid] = vmax; s_pi[wid] = vidx; }
    __syncthreads();
    if (t == 0) {
        float gm = s_pm[0]; int gi = s_pi[0];
        #pragma unroll
        for (int wv = 1; wv < 4; ++wv) {
            float ov = s_pm[wv]; int oi = s_pi[wv];
            if (ov > gm || (ov == gm && oi < gi)) { gm = ov; gi = oi; }
        }
        s_gmax = gm; s_gidx = gi;
    }
    __syncthreads();
    const float gmax = s_gmax;

    float z = 0.f, wx = 0.f, wy = 0.f;
    #pragma unroll
    for (int p = 0; p < 16; ++p) {
        int i4 = p * 256 + t;
        float4 v = *(const float4*)&rowbuf[i4 * 4];
        int i = i4 * 4;
        float e0 = __expf(v.x - gmax), e1 = __expf(v.y - gmax);
        float e2 = __expf(v.z - gmax), e3 = __expf(v.w - gmax);
        z += (e0 + e1) + (e2 + e3);
        float cy = (float)(i >> 7) + 0.5f;
        float cx0 = (float)(i & (Ww - 1)) + 0.5f;
        wx += e0 * cx0 + e1 * (cx0 + 1.f) + e2 * (cx0 + 2.f) + e3 * (cx0 + 3.f);
        wy += (e0 + e1 + e2 + e3) * cy;
    }
    #pragma unroll
    for (int off = 32; off > 0; off >>= 1) {
        z  += __shfl_down(z, off);
        wx += __shfl_down(wx, off);
        wy += __shfl_down(wy, off);
    }
    if (lane == 0) { s_red[wid][0] = z; s_red[wid][1] = wx; s_red[wid][2] = wy; }
    __syncthreads();

    if (t == 0) {
        float Z = 0.f, WX = 0.f, WY = 0.f;
        #pragma unroll
        for (int wv = 0; wv < 4; ++wv) { Z += s_red[wv][0]; WX += s_red[wv][1]; WY += s_red[wv][2]; }

        out[(size_t)row * 2 + 0] = (WX / Z) * (1.0f / (float)Ww);
        out[(size_t)row * 2 + 1] = (WY / Z) * (1.0f / (float)Hh);

        // local 3x3 around argmax (reshape(bs,nq,w,h): r = k / 128, c = k % 128)
        int p  = s_gidx;
        int pr = p / Hh;
        int pc = p % Hh;
        float lsum = 0.f, lwx = 0.f, lwy = 0.f;
        #pragma unroll
        for (int di = -1; di <= 1; ++di) {
            #pragma unroll
            for (int dj = -1; dj <= 1; ++dj) {
                int r = pr + di, c = pc + dj;
                if (r >= 0 && r < Ww && c >= 0 && c < Hh) {
                    int k = r * Hh + c;
                    float e = __expf(rowbuf[k] - gmax);
                    lsum += e;
                    lwx  += e * ((float)(k & (Ww - 1)) + 0.5f);
                    lwy  += e * ((float)(k >> 7) + 0.5f);
                }
            }
        }
        float denom = lsum + 1e-10f * Z;
        out[PROPS_OFF + (size_t)row * 2 + 0] = (lwx / denom) * (1.0f / (float)Ww);
        out[PROPS_OFF + (size_t)row * 2 + 1] = (lwy / denom) * (1.0f / (float)Hh);
    }
}

extern "C" void kernel_launch(void* const* d_in, const int* in_sizes, int n_in,
                              void* d_out, int out_size, void* d_ws, size_t ws_size,
                              hipStream_t stream) {
    const float* Q = (const float*)d_in[0];   // [hw, bs, c]
    const float* S = (const float*)d_in[1];   // [nq, bs, c]
    float* out = (float*)d_out;

    const size_t splitElems = (size_t)BS * NQP * C;         // 458752
    const size_t wsNeeded = splitElems * 2 * sizeof(_Float16);

    if (ws_size >= wsNeeded) {
        _Float16* shi = (_Float16*)d_ws;
        _Float16* slo = shi + splitElems;
        split_S_kernel<<<dim3((splitElems / 4 + 255) / 256), 256, 0, stream>>>(S, shi, slo);
        gemm_kernel<true><<<dim3(HW / BM, BS), 256, 0, stream>>>(Q, S, shi, slo, out);
    } else {
        gemm_kernel<false><<<dim3(HW / BM, BS), 256, 0, stream>>>(Q, S, nullptr, nullptr, out);
    }
    reduce_kernel<<<dim3(BS * NQ), 256, 0, stream>>>(out + SIM_OFF, out);
}